// Round 1
// baseline (2309.518 us; speedup 1.0000x reference)
//
#include <hip/hip_runtime.h>
#include <hip/hip_bf16.h>

// Problem constants (static per reference)
#define NTOK 16384   // B*T
#define HD   512     // H
#define ED   8       // E experts
#define FD   2048    // F
#define CAP  5120    // capacity per expert
#define NA   32768   // NTOK * K(=2) assignments

// Workspace layout (bytes)
static constexpr size_t OFF_EIDX = 0;                       // int[NA]
static constexpr size_t OFF_WGT  = OFF_EIDX + (size_t)NA*4; // float[NA]
static constexpr size_t OFF_SLOT = OFF_WGT  + (size_t)NA*4; // int[NA]
static constexpr size_t OFF_STOK = OFF_SLOT + (size_t)NA*4; // int[ED*CAP]
static constexpr size_t OFF_H    = 1u << 20;                // bf16[ED*CAP*FD]
static constexpr size_t OFF_EOUT = OFF_H + (size_t)ED*CAP*FD*2; // float[ED*CAP*HD]
// total ≈ 253 MB

// ---------------------------------------------------------------------------
// Router: logits = x @ router_w, top-2 (ties -> lower index), softmax over 2.
// One wave per token; router_w (16 KB) staged in LDS.
// ---------------------------------------------------------------------------
__global__ __launch_bounds__(256) void router_kernel(
    const float* __restrict__ x, const float* __restrict__ rw,
    int* __restrict__ eidx, float* __restrict__ wgt)
{
    __shared__ float rws[HD * ED];  // 16 KB
    const int tid = threadIdx.x;
    for (int i = tid * 4; i < HD * ED; i += 256 * 4) {
        *(float4*)(rws + i) = *(const float4*)(rw + i);
    }
    __syncthreads();

    const int wid = tid >> 6, lane = tid & 63;
    const int t = blockIdx.x * 4 + wid;
    const float* xr = x + (size_t)t * HD;

    float acc[ED];
#pragma unroll
    for (int e = 0; e < ED; e++) acc[e] = 0.f;

    float4 xv0 = *(const float4*)(xr + lane * 8);
    float4 xv1 = *(const float4*)(xr + lane * 8 + 4);
    float xv[8] = {xv0.x, xv0.y, xv0.z, xv0.w, xv1.x, xv1.y, xv1.z, xv1.w};
#pragma unroll
    for (int j = 0; j < 8; j++) {
        const int h = lane * 8 + j;
#pragma unroll
        for (int e = 0; e < ED; e++) acc[e] += xv[j] * rws[h * ED + e];
    }
    // wave64 reduction
#pragma unroll
    for (int off = 32; off >= 1; off >>= 1) {
#pragma unroll
        for (int e = 0; e < ED; e++) acc[e] += __shfl_down(acc[e], off);
    }
    if (lane == 0) {
        int e0 = 0; float l0 = acc[0];
        for (int e = 1; e < ED; e++) if (acc[e] > l0) { l0 = acc[e]; e0 = e; }
        int e1 = 0; float l1 = -1e30f;
        for (int e = 0; e < ED; e++) {
            if (e == e0) continue;
            if (acc[e] > l1) { l1 = acc[e]; e1 = e; }
        }
        const float ex = expf(l1 - l0);     // l0 >= l1
        const float inv = 1.f / (1.f + ex);
        eidx[t * 2 + 0] = e0;  eidx[t * 2 + 1] = e1;
        wgt [t * 2 + 0] = inv; wgt [t * 2 + 1] = ex * inv;
    }
}

// ---------------------------------------------------------------------------
// Deterministic slot assignment (stable-sort-by-expert semantics).
// Single block, 1024 threads, 32 chunks. slot = running[e] + rank-in-chunk.
// Writes: slotA[a] (clamped 0 if dropped), wgt[a] (0 if dropped),
//         stok[e*CAP+slot] = token (else -1).
// ---------------------------------------------------------------------------
__global__ __launch_bounds__(1024) void scan_kernel(
    const int* __restrict__ eidx, float* __restrict__ wgt,
    int* __restrict__ slotA, int* __restrict__ stok)
{
    __shared__ int running[ED];
    __shared__ int wcnt[16][ED];
    const int tid = threadIdx.x;

    for (int i = tid; i < ED * CAP; i += 1024) stok[i] = -1;
    if (tid < ED) running[tid] = 0;
    __syncthreads();

    const int lane = tid & 63, wid = tid >> 6;
    const unsigned long long below = (1ull << lane) - 1ull;

    for (int c = 0; c < NA / 1024; c++) {
        const int a = c * 1024 + tid;
        const int e = eidx[a];
        const float w = wgt[a];
        int myrank = 0;
#pragma unroll
        for (int ee = 0; ee < ED; ee++) {
            unsigned long long m = __ballot(e == ee);
            if (ee == e) myrank = __popcll(m & below);
            if (lane == 0) wcnt[wid][ee] = __popcll(m);
        }
        __syncthreads();
        int woff = 0;
        for (int ww = 0; ww < wid; ww++) woff += wcnt[ww][e];
        const int slot = running[e] + woff + myrank;
        const bool keep = slot < CAP;
        slotA[a] = keep ? slot : 0;
        wgt[a]   = keep ? w : 0.f;
        if (keep) stok[e * CAP + slot] = a >> 1;  // token = a / K
        __syncthreads();
        if (tid < ED) {
            int tot = 0;
            for (int ww = 0; ww < 16; ww++) tot += wcnt[ww][tid];
            running[tid] += tot;
        }
        __syncthreads();
    }
}

__device__ __forceinline__ float gelu_tanh(float v) {
    return 0.5f * v * (1.f + tanhf(0.7978845608028654f * (v + 0.044715f * v * v * v)));
}

// ---------------------------------------------------------------------------
// GEMM1: h[e] = gelu(gather(x)[CAPxHD] @ w1[e][HDxFD] + b1[e]) -> bf16
// 64x64 tile, BK=16, 256 threads, 4x4 acc/thread.
// ---------------------------------------------------------------------------
__global__ __launch_bounds__(256) void gemm1_kernel(
    const float* __restrict__ x, const float* __restrict__ w1,
    const float* __restrict__ b1, const int* __restrict__ stok,
    __hip_bfloat16* __restrict__ hbuf)
{
    __shared__ float As[16 * 68];  // [k][m], padded stride 68
    __shared__ float Bs[16 * 64];  // [k][n]
    const int tid = threadIdx.x;
    const int e  = blockIdx.z;
    const int m0 = blockIdx.y * 64;
    const int n0 = blockIdx.x * 64;

    const int lm = tid >> 2;         // staging row 0..63
    const int kq = tid & 3;          // k-quad 0..3
    const int tok = stok[e * CAP + m0 + lm];
    const float* arow = (tok >= 0) ? (x + (size_t)tok * HD) : nullptr;

    const int bk = tid >> 4;         // 0..15
    const int bn = (tid & 15) * 4;   // 0..60
    const float* bbase = w1 + (size_t)e * HD * FD + n0 + bn;

    const int tx = tid & 15, ty = tid >> 4;
    float acc[4][4];
#pragma unroll
    for (int i = 0; i < 4; i++)
#pragma unroll
        for (int j = 0; j < 4; j++) acc[i][j] = 0.f;

    for (int k0 = 0; k0 < HD; k0 += 16) {
        float4 av = make_float4(0.f, 0.f, 0.f, 0.f);
        if (arow) av = *(const float4*)(arow + k0 + kq * 4);
        const float4 bv = *(const float4*)(bbase + (size_t)(k0 + bk) * FD);
        __syncthreads();
        As[(kq * 4 + 0) * 68 + lm] = av.x;
        As[(kq * 4 + 1) * 68 + lm] = av.y;
        As[(kq * 4 + 2) * 68 + lm] = av.z;
        As[(kq * 4 + 3) * 68 + lm] = av.w;
        *(float4*)(&Bs[bk * 64 + bn]) = bv;
        __syncthreads();
#pragma unroll
        for (int k = 0; k < 16; k++) {
            const float4 a = *(const float4*)(&As[k * 68 + ty * 4]);
            const float4 b = *(const float4*)(&Bs[k * 64 + tx * 4]);
            const float aa[4] = {a.x, a.y, a.z, a.w};
            const float bb[4] = {b.x, b.y, b.z, b.w};
#pragma unroll
            for (int i = 0; i < 4; i++)
#pragma unroll
                for (int j = 0; j < 4; j++) acc[i][j] += aa[i] * bb[j];
        }
    }
#pragma unroll
    for (int i = 0; i < 4; i++) {
        const int m = m0 + ty * 4 + i;
        union { __hip_bfloat16 h[4]; uint2 u; } pk;
#pragma unroll
        for (int j = 0; j < 4; j++) {
            const float v = acc[i][j] + b1[e * FD + n0 + tx * 4 + j];
            pk.h[j] = __float2bfloat16(gelu_tanh(v));
        }
        *(uint2*)(hbuf + (size_t)(e * CAP + m) * FD + n0 + tx * 4) = pk.u;
    }
}

// ---------------------------------------------------------------------------
// GEMM2: eout[e] = h[e][CAPxFD](bf16) @ w2[e][FDxHD] + b2[e]  -> fp32
// ---------------------------------------------------------------------------
__global__ __launch_bounds__(256) void gemm2_kernel(
    const __hip_bfloat16* __restrict__ hbuf, const float* __restrict__ w2,
    const float* __restrict__ b2, float* __restrict__ eout)
{
    __shared__ float As[16 * 68];
    __shared__ float Bs[16 * 64];
    const int tid = threadIdx.x;
    const int e  = blockIdx.z;
    const int m0 = blockIdx.y * 64;
    const int n0 = blockIdx.x * 64;

    const int lm = tid >> 2;
    const int kq = tid & 3;
    const __hip_bfloat16* arow = hbuf + (size_t)(e * CAP + m0 + lm) * FD;

    const int bk = tid >> 4;
    const int bn = (tid & 15) * 4;
    const float* bbase = w2 + (size_t)e * FD * HD + n0 + bn;

    const int tx = tid & 15, ty = tid >> 4;
    float acc[4][4];
#pragma unroll
    for (int i = 0; i < 4; i++)
#pragma unroll
        for (int j = 0; j < 4; j++) acc[i][j] = 0.f;

    for (int k0 = 0; k0 < FD; k0 += 16) {
        uint2 raw = *(const uint2*)(arow + k0 + kq * 4);
        const float4 bv = *(const float4*)(bbase + (size_t)(k0 + bk) * HD);
        __syncthreads();
        const __hip_bfloat16* hp = (const __hip_bfloat16*)&raw;
        As[(kq * 4 + 0) * 68 + lm] = __bfloat162float(hp[0]);
        As[(kq * 4 + 1) * 68 + lm] = __bfloat162float(hp[1]);
        As[(kq * 4 + 2) * 68 + lm] = __bfloat162float(hp[2]);
        As[(kq * 4 + 3) * 68 + lm] = __bfloat162float(hp[3]);
        *(float4*)(&Bs[bk * 64 + bn]) = bv;
        __syncthreads();
#pragma unroll
        for (int k = 0; k < 16; k++) {
            const float4 a = *(const float4*)(&As[k * 68 + ty * 4]);
            const float4 b = *(const float4*)(&Bs[k * 64 + tx * 4]);
            const float aa[4] = {a.x, a.y, a.z, a.w};
            const float bb[4] = {b.x, b.y, b.z, b.w};
#pragma unroll
            for (int i = 0; i < 4; i++)
#pragma unroll
                for (int j = 0; j < 4; j++) acc[i][j] += aa[i] * bb[j];
        }
    }
#pragma unroll
    for (int i = 0; i < 4; i++) {
        const int m = m0 + ty * 4 + i;
        float4 o;
        o.x = acc[i][0] + b2[e * HD + n0 + tx * 4 + 0];
        o.y = acc[i][1] + b2[e * HD + n0 + tx * 4 + 1];
        o.z = acc[i][2] + b2[e * HD + n0 + tx * 4 + 2];
        o.w = acc[i][3] + b2[e * HD + n0 + tx * 4 + 3];
        *(float4*)(eout + (size_t)(e * CAP + m) * HD + n0 + tx * 4) = o;
    }
}

// ---------------------------------------------------------------------------
// Combine: out[t] = w0 * eout[e0, s0] + w1 * eout[e1, s1]. One wave per token.
// Dropped assignments have weight 0 (slot clamped to 0, valid memory).
// ---------------------------------------------------------------------------
__global__ __launch_bounds__(256) void combine_kernel(
    const float* __restrict__ eout, const int* __restrict__ eidx,
    const int* __restrict__ slotA, const float* __restrict__ wgt,
    float* __restrict__ out)
{
    const int tid = threadIdx.x;
    const int wid = tid >> 6, lane = tid & 63;
    const int t = blockIdx.x * 4 + wid;

    const int e0 = eidx[t * 2], e1 = eidx[t * 2 + 1];
    const int s0 = slotA[t * 2], s1 = slotA[t * 2 + 1];
    const float w0 = wgt[t * 2], w1 = wgt[t * 2 + 1];

    const float* r0 = eout + (size_t)(e0 * CAP + s0) * HD;
    const float* r1 = eout + (size_t)(e1 * CAP + s1) * HD;
    float* o = out + (size_t)t * HD;
    const int base = lane * 8;
#pragma unroll
    for (int q = 0; q < 2; q++) {
        const float4 a = *(const float4*)(r0 + base + q * 4);
        const float4 b = *(const float4*)(r1 + base + q * 4);
        float4 r;
        r.x = w0 * a.x + w1 * b.x;
        r.y = w0 * a.y + w1 * b.y;
        r.z = w0 * a.z + w1 * b.z;
        r.w = w0 * a.w + w1 * b.w;
        *(float4*)(o + base + q * 4) = r;
    }
}

extern "C" void kernel_launch(void* const* d_in, const int* in_sizes, int n_in,
                              void* d_out, int out_size, void* d_ws, size_t ws_size,
                              hipStream_t stream)
{
    const float* x  = (const float*)d_in[0];
    const float* rw = (const float*)d_in[1];
    const float* w1 = (const float*)d_in[2];
    const float* b1 = (const float*)d_in[3];
    const float* w2 = (const float*)d_in[4];
    const float* b2 = (const float*)d_in[5];
    float* out = (float*)d_out;

    char* ws = (char*)d_ws;
    int*   eidx  = (int*)  (ws + OFF_EIDX);
    float* wgt   = (float*)(ws + OFF_WGT);
    int*   slotA = (int*)  (ws + OFF_SLOT);
    int*   stok  = (int*)  (ws + OFF_STOK);
    __hip_bfloat16* hbuf = (__hip_bfloat16*)(ws + OFF_H);
    float* eout  = (float*)(ws + OFF_EOUT);

    router_kernel<<<NTOK / 4, 256, 0, stream>>>(x, rw, eidx, wgt);
    scan_kernel<<<1, 1024, 0, stream>>>(eidx, wgt, slotA, stok);

    dim3 g1(FD / 64, CAP / 64, ED);   // 32 x 80 x 8
    gemm1_kernel<<<g1, 256, 0, stream>>>(x, w1, b1, stok, hbuf);

    dim3 g2(HD / 64, CAP / 64, ED);   // 8 x 80 x 8
    gemm2_kernel<<<g2, 256, 0, stream>>>(hbuf, w2, b2, eout);

    combine_kernel<<<NTOK / 4, 256, 0, stream>>>(eout, eidx, slotA, wgt, out);
}

// Round 2
// 739.734 us; speedup vs baseline: 3.1221x; 3.1221x over previous
//
#include <hip/hip_runtime.h>
#include <hip/hip_bf16.h>

// Problem constants (static per reference)
#define NTOK 16384   // B*T
#define HD   512     // H
#define ED   8       // E experts
#define FD   2048    // F
#define CAP  5120    // capacity per expert
#define NA   32768   // NTOK * K(=2)

typedef __bf16 bf16x8 __attribute__((ext_vector_type(8)));
typedef float  f32x4  __attribute__((ext_vector_type(4)));

// Workspace layout (bytes). Total ~218 MB (known-good budget >= 253 MB).
static constexpr size_t OFF_EIDX = 0;                                  // int[NA]
static constexpr size_t OFF_WGT  = 131072;                             // float[NA]
static constexpr size_t OFF_STOK = 262144;                             // int[ED*CAP]
static constexpr size_t OFF_SWGT = 458752;                             // float[ED*CAP]
static constexpr size_t OFF_W2T  = 1u << 20;                           // bf16[ED][HD][FD]
static constexpr size_t OFF_H    = OFF_W2T + (size_t)ED*HD*FD*2;       // bf16[ED][CAP][FD]
static constexpr size_t OFF_W1T  = OFF_H   + (size_t)ED*CAP*FD*2;      // bf16[ED][FD][HD]
static constexpr size_t OFF_XBF  = OFF_W1T + (size_t)ED*FD*HD*2;       // bf16[NTOK][HD]

__device__ __forceinline__ unsigned short f2bf(float f) {
    __bf16 b = (__bf16)f;
    return __builtin_bit_cast(unsigned short, b);
}

__device__ __forceinline__ void gl16(const unsigned short* src, unsigned short* lds_dst) {
    __builtin_amdgcn_global_load_lds(
        (const __attribute__((address_space(1))) void*)src,
        (__attribute__((address_space(3))) void*)lds_dst, 16, 0, 0);
}

__device__ __forceinline__ float gelu_tanh(float v) {
    return 0.5f * v * (1.f + tanhf(0.7978845608028654f * (v + 0.044715f * v * v * v)));
}

// ---------------------------------------------------------------------------
// Prep: fp32 -> bf16 cast (x), and cast+transpose (weights)
// ---------------------------------------------------------------------------
__global__ __launch_bounds__(256) void cast_x_kernel(
    const float4* __restrict__ x, ushort4* __restrict__ xb)
{
    const int i = blockIdx.x * 256 + threadIdx.x;
    float4 v = x[i];
    ushort4 o;
    o.x = f2bf(v.x); o.y = f2bf(v.y); o.z = f2bf(v.z); o.w = f2bf(v.w);
    xb[i] = o;
}

// in: [R][C] fp32 (per expert)  ->  out: [C][R] bf16 (per expert)
__global__ __launch_bounds__(256) void transpose_cast_kernel(
    const float* __restrict__ in, unsigned short* __restrict__ out, int R, int C)
{
    __shared__ unsigned short tile[32][33];
    const int e = blockIdx.z;
    in  += (size_t)e * R * C;
    out += (size_t)e * R * C;
    const int r0 = blockIdx.y * 32, c0 = blockIdx.x * 32;
    const int tr = threadIdx.x >> 3, tc = (threadIdx.x & 7) * 4;
    const float4 v = *(const float4*)(in + (size_t)(r0 + tr) * C + c0 + tc);
    tile[tr][tc + 0] = f2bf(v.x);
    tile[tr][tc + 1] = f2bf(v.y);
    tile[tr][tc + 2] = f2bf(v.z);
    tile[tr][tc + 3] = f2bf(v.w);
    __syncthreads();
    ushort4 o;
    o.x = tile[tc + 0][tr]; o.y = tile[tc + 1][tr];
    o.z = tile[tc + 2][tr]; o.w = tile[tc + 3][tr];
    *(ushort4*)(out + (size_t)(c0 + tr) * R + r0 + tc) = o;
}

// ---------------------------------------------------------------------------
// Router: logits = x @ router_w (exact fp32), top-2, softmax over the 2.
// ---------------------------------------------------------------------------
__global__ __launch_bounds__(256) void router_kernel(
    const float* __restrict__ x, const float* __restrict__ rw,
    int* __restrict__ eidx, float* __restrict__ wgt)
{
    __shared__ float rws[HD * ED];
    const int tid = threadIdx.x;
    for (int i = tid * 4; i < HD * ED; i += 256 * 4)
        *(float4*)(rws + i) = *(const float4*)(rw + i);
    __syncthreads();

    const int wid = tid >> 6, lane = tid & 63;
    const int t = blockIdx.x * 4 + wid;
    const float* xr = x + (size_t)t * HD;

    float acc[ED];
#pragma unroll
    for (int e = 0; e < ED; e++) acc[e] = 0.f;

    float4 xv0 = *(const float4*)(xr + lane * 8);
    float4 xv1 = *(const float4*)(xr + lane * 8 + 4);
    float xv[8] = {xv0.x, xv0.y, xv0.z, xv0.w, xv1.x, xv1.y, xv1.z, xv1.w};
#pragma unroll
    for (int j = 0; j < 8; j++) {
        const int h = lane * 8 + j;
#pragma unroll
        for (int e = 0; e < ED; e++) acc[e] += xv[j] * rws[h * ED + e];
    }
#pragma unroll
    for (int off = 32; off >= 1; off >>= 1) {
#pragma unroll
        for (int e = 0; e < ED; e++) acc[e] += __shfl_down(acc[e], off);
    }
    if (lane == 0) {
        int e0 = 0; float l0 = acc[0];
        for (int e = 1; e < ED; e++) if (acc[e] > l0) { l0 = acc[e]; e0 = e; }
        int e1 = 0; float l1 = -1e30f;
        for (int e = 0; e < ED; e++) {
            if (e == e0) continue;
            if (acc[e] > l1) { l1 = acc[e]; e1 = e; }
        }
        const float ex = expf(l1 - l0);
        const float inv = 1.f / (1.f + ex);
        eidx[t * 2 + 0] = e0;  eidx[t * 2 + 1] = e1;
        wgt [t * 2 + 0] = inv; wgt [t * 2 + 1] = ex * inv;
    }
}

// ---------------------------------------------------------------------------
// Deterministic slot assignment (stable-sort-by-expert semantics).
// Outputs: stok[e*CAP+slot]=token (-1 if unfilled), swgt[e*CAP+slot]=weight.
// ---------------------------------------------------------------------------
__global__ __launch_bounds__(1024) void scan_kernel(
    const int* __restrict__ eidx, const float* __restrict__ wgt,
    int* __restrict__ stok, float* __restrict__ swgt)
{
    __shared__ int running[ED];
    __shared__ int wcnt[16][ED];
    const int tid = threadIdx.x;

    for (int i = tid; i < ED * CAP; i += 1024) stok[i] = -1;
    if (tid < ED) running[tid] = 0;
    __syncthreads();

    const int lane = tid & 63, wid = tid >> 6;
    const unsigned long long below = (1ull << lane) - 1ull;

    for (int c = 0; c < NA / 1024; c++) {
        const int a = c * 1024 + tid;
        const int e = eidx[a];
        const float w = wgt[a];
        int myrank = 0;
#pragma unroll
        for (int ee = 0; ee < ED; ee++) {
            unsigned long long m = __ballot(e == ee);
            if (ee == e) myrank = __popcll(m & below);
            if (lane == 0) wcnt[wid][ee] = __popcll(m);
        }
        __syncthreads();
        int woff = 0;
        for (int ww = 0; ww < wid; ww++) woff += wcnt[ww][e];
        const int slot = running[e] + woff + myrank;
        if (slot < CAP) {
            stok[e * CAP + slot] = a >> 1;   // token = a / K
            swgt[e * CAP + slot] = w;
        }
        __syncthreads();
        if (tid < ED) {
            int tot = 0;
            for (int ww = 0; ww < 16; ww++) tot += wcnt[ww][tid];
            running[tid] += tot;
        }
        __syncthreads();
    }
}

// ---------------------------------------------------------------------------
// MFMA GEMM (m97 structure): 128x128 tile, BK=32, 4 waves (2x2), 4x4 frags.
// A: [rows][KD] bf16 (gathered via stok when !FUSE). Bt: [ED][ND][KD] bf16.
// FUSE=false: out = gelu(A@B + bias) -> bf16 hout (hbuf).
// FUSE=true : atomicAdd(out[tok] , (A@B + bias) * swgt) (fused combine).
// ---------------------------------------------------------------------------
template<int KD, int ND, bool FUSE>
__global__ __launch_bounds__(256) void gemm_mfma(
    const unsigned short* __restrict__ Abase,
    const unsigned short* __restrict__ Bt,
    const float* __restrict__ bias,
    const int* __restrict__ stok,
    const float* __restrict__ swgt,
    unsigned short* __restrict__ hout,
    float* __restrict__ out)
{
    __shared__ __align__(16) unsigned short As[4 * 128 * 8];  // [kchunk][row][8]
    __shared__ __align__(16) unsigned short Bs[4 * 128 * 8];

    const int tid = threadIdx.x;
    const int e  = blockIdx.z;
    const int m0 = blockIdx.y * 128;
    const int n0 = blockIdx.x * 128;

    // Staging assignment: thread handles row rA, chunks c0 and c0+2 (16B each)
    const int rA = tid & 127;
    const int c0 = tid >> 7;

    size_t arow_idx;
    if (!FUSE) {
        const int tok = stok[e * CAP + m0 + rA];
        arow_idx = (size_t)(tok >= 0 ? tok : 0);       // dropped -> row 0 (weight 0 kills it)
    } else {
        arow_idx = (size_t)(e * CAP + m0 + rA);
    }
    const unsigned short* arow = Abase + arow_idx * KD;
    const unsigned short* brow = Bt + ((size_t)e * ND + n0 + rA) * KD;

    unsigned short* AsP0 = &As[((c0)     * 128 + rA) * 8];
    unsigned short* AsP1 = &As[((c0 + 2) * 128 + rA) * 8];
    unsigned short* BsP0 = &Bs[((c0)     * 128 + rA) * 8];
    unsigned short* BsP1 = &Bs[((c0 + 2) * 128 + rA) * 8];

    const int lane = tid & 63;
    const int wid  = tid >> 6;
    const int wrow = (wid & 1) * 64;
    const int wcol = (wid >> 1) * 64;
    const int l15  = lane & 15;
    const int quad = lane >> 4;

    f32x4 acc[4][4];
#pragma unroll
    for (int i = 0; i < 4; i++)
#pragma unroll
        for (int j = 0; j < 4; j++) acc[i][j] = (f32x4)0.f;

    const bf16x8* Av = (const bf16x8*)As;
    const bf16x8* Bv = (const bf16x8*)Bs;
    const int aoff = quad * 128 + wrow + l15;
    const int boff = quad * 128 + wcol + l15;

    for (int k0 = 0; k0 < KD; k0 += 32) {
        __syncthreads();   // previous iter's LDS reads complete
        gl16(arow + k0 + c0 * 8,       AsP0);
        gl16(arow + k0 + (c0 + 2) * 8, AsP1);
        gl16(brow + k0 + c0 * 8,       BsP0);
        gl16(brow + k0 + (c0 + 2) * 8, BsP1);
        __syncthreads();   // staging landed (barrier drains vmcnt)

        bf16x8 af[4], bfv[4];
#pragma unroll
        for (int i = 0; i < 4; i++) af[i]  = Av[aoff + i * 16];
#pragma unroll
        for (int j = 0; j < 4; j++) bfv[j] = Bv[boff + j * 16];
#pragma unroll
        for (int i = 0; i < 4; i++)
#pragma unroll
            for (int j = 0; j < 4; j++)
                acc[i][j] = __builtin_amdgcn_mfma_f32_16x16x32_bf16(af[i], bfv[j], acc[i][j], 0, 0, 0);
    }

    // Epilogue. C/D layout: col = lane&15, row = quad*4 + reg.
    if (!FUSE) {
#pragma unroll
        for (int i = 0; i < 4; i++) {
#pragma unroll
            for (int g = 0; g < 4; g++) {
                const int m = wrow + i * 16 + quad * 4 + g;
                unsigned short* hrow = hout + ((size_t)e * CAP + m0 + m) * FD + n0;
#pragma unroll
                for (int j = 0; j < 4; j++) {
                    const int n = wcol + j * 16 + l15;
                    const float v = acc[i][j][g] + bias[(size_t)e * ND + n0 + n];
                    hrow[n] = f2bf(gelu_tanh(v));
                }
            }
        }
    } else {
#pragma unroll
        for (int i = 0; i < 4; i++) {
#pragma unroll
            for (int g = 0; g < 4; g++) {
                const int m = wrow + i * 16 + quad * 4 + g;
                const int tok = stok[e * CAP + m0 + m];
                if (tok >= 0) {
                    const float w = swgt[e * CAP + m0 + m];
                    float* orow = out + (size_t)tok * HD + n0;
#pragma unroll
                    for (int j = 0; j < 4; j++) {
                        const int n = wcol + j * 16 + l15;
                        const float v = (acc[i][j][g] + bias[(size_t)e * ND + n0 + n]) * w;
                        atomicAdd(orow + n, v);
                    }
                }
            }
        }
    }
}

extern "C" void kernel_launch(void* const* d_in, const int* in_sizes, int n_in,
                              void* d_out, int out_size, void* d_ws, size_t ws_size,
                              hipStream_t stream)
{
    const float* x  = (const float*)d_in[0];
    const float* rw = (const float*)d_in[1];
    const float* w1 = (const float*)d_in[2];
    const float* b1 = (const float*)d_in[3];
    const float* w2 = (const float*)d_in[4];
    const float* b2 = (const float*)d_in[5];
    float* out = (float*)d_out;

    char* ws = (char*)d_ws;
    int*   eidx = (int*)  (ws + OFF_EIDX);
    float* wgt  = (float*)(ws + OFF_WGT);
    int*   stok = (int*)  (ws + OFF_STOK);
    float* swgt = (float*)(ws + OFF_SWGT);
    unsigned short* w2t  = (unsigned short*)(ws + OFF_W2T);
    unsigned short* hbuf = (unsigned short*)(ws + OFF_H);
    unsigned short* w1t  = (unsigned short*)(ws + OFF_W1T);
    unsigned short* xbf  = (unsigned short*)(ws + OFF_XBF);

    // Prep: casts + transposes + router + routing scan (independent of GEMMs)
    cast_x_kernel<<<NTOK * HD / 1024, 256, 0, stream>>>((const float4*)x, (ushort4*)xbf);
    transpose_cast_kernel<<<dim3(FD / 32, HD / 32, ED), 256, 0, stream>>>(w1, w1t, HD, FD);
    transpose_cast_kernel<<<dim3(HD / 32, FD / 32, ED), 256, 0, stream>>>(w2, w2t, FD, HD);
    router_kernel<<<NTOK / 4, 256, 0, stream>>>(x, rw, eidx, wgt);
    scan_kernel<<<1, 1024, 0, stream>>>(eidx, wgt, stok, swgt);
    hipMemsetAsync(d_out, 0, (size_t)out_size * sizeof(float), stream);

    // GEMM1: h = gelu(gather(x) @ w1 + b1)  [bf16 out]
    gemm_mfma<HD, FD, false><<<dim3(FD / 128, CAP / 128, ED), 256, 0, stream>>>(
        xbf, w1t, b1, stok, nullptr, hbuf, nullptr);

    // GEMM2 + fused combine: out[tok] += (h @ w2 + b2) * weight
    gemm_mfma<FD, HD, true><<<dim3(HD / 128, CAP / 128, ED), 256, 0, stream>>>(
        hbuf, w2t, b2, stok, swgt, nullptr, out);
}